// Round 4
// baseline (6579.241 us; speedup 1.0000x reference)
//
#include <hip/hip_runtime.h>
#include <hip/hip_cooperative_groups.h>
#include <stdint.h>

namespace cg = cooperative_groups;

#define T_  64
#define A_  256
#define GG_ 16
#define H_  128

// ---- workspace layout (float offsets) ----
#define OFF_WCATT 0          // WcatT: [256 col][512 q]
#define OFF_BSUM  131072     // [512]
#define OFF_S     131584     // S: [256 k][1024 j]
#define OFF_H     393728     // h state: [256][128]
#define OFF_C     426496     // c state: [256][128]
#define OFF_FLAG  459264     // int flag (mask encoding mode)
#define IDX_OFF_BYTES 2097152ULL   // uint8 sparse indices (aligned)

__device__ __forceinline__ float sigf(float x){ return 1.0f/(1.0f+__expf(-x)); }
__device__ __forceinline__ float tanhfast(float x){ float e = __expf(2.0f*x); return 1.0f - 2.0f/(e+1.0f); }

__device__ __forceinline__ bool maskAt(const void* m, int mode, int i){
  if (mode == 0) return ((const int*)m)[i] != 0;
  if (mode == 2) return ((const float*)m)[i] != 0.0f;
  return ((const unsigned char*)m)[i] != 0;
}

// ---- detect mask encoding: 0=int32, 1=uint8/bool, 2=float32 ----
__global__ void k_maskmode(const unsigned* m, int* flag){
  __shared__ int r_int[256]; __shared__ int r_flt[256];
  int ok_int = 1, ok_flt = 1;
  for (int i = threadIdx.x; i < 4096; i += 256){
    unsigned v = m[i];
    if (v > 1u) ok_int = 0;
    if (v != 0u && v != 0x3F800000u) ok_flt = 0;
  }
  r_int[threadIdx.x]=ok_int; r_flt[threadIdx.x]=ok_flt; __syncthreads();
  for (int s=128;s>0;s>>=1){
    if (threadIdx.x<s){ r_int[threadIdx.x]&=r_int[threadIdx.x+s]; r_flt[threadIdx.x]&=r_flt[threadIdx.x+s]; }
    __syncthreads();
  }
  if (threadIdx.x==0) *flag = r_int[0] ? 0 : (r_flt[0] ? 2 : 1);
}

// ---- init: WcatT transpose + bias sum ----
__global__ void k_init(const float* __restrict__ W_ih, const float* __restrict__ W_hh,
                       const float* __restrict__ b_ih, const float* __restrict__ b_hh,
                       float* __restrict__ ws){
  const int n = 131072 + 512;
  for (int id = blockIdx.x*blockDim.x + threadIdx.x; id < n; id += gridDim.x*blockDim.x){
    if (id < 131072){
      int col = id >> 9, q = id & 511;
      ws[OFF_WCATT + id] = (col < 128) ? W_ih[q*128+col] : W_hh[q*128+col-128];
    } else {
      int q = id - 131072; ws[OFF_BSUM + q] = b_ih[q] + b_hh[q];
    }
  }
}

// ---- sparse-encode grid: per (t,a,g) row of 256, compact nonzero k (uint8) ----
__global__ void k_encode(const float* __restrict__ grid, unsigned char* __restrict__ idx,
                         unsigned char* __restrict__ cnt, int CAP){
  int wave = threadIdx.x >> 6, lane = threadIdx.x & 63;
  long long row = (long long)blockIdx.x*4 + wave;   // < 262144
  const float4 v = *(const float4*)(grid + row*256 + lane*4);
  unsigned long long lt = (lane == 0) ? 0ULL : ((1ULL << lane) - 1ULL);
  int base = 0;
  #pragma unroll
  for (int i=0;i<4;i++){
    float x = (i==0)?v.x:(i==1)?v.y:(i==2)?v.z:v.w;
    bool nz = (x != 0.0f);
    unsigned long long m = __ballot(nz);
    int pos = base + __popcll(m & lt);
    if (nz && pos < CAP) idx[(size_t)row*CAP + pos] = (unsigned char)(lane*4+i);
    base += __popcll(m);
  }
  if (lane==0) cnt[row] = (unsigned char)(base < CAP ? base : CAP);
}

// ---- persistent cooperative kernel: whole 64-step recurrence ----
// grid 256 blocks x 256 threads. Phase A: block b owns S columns [4b,4b+4).
// Phase B: block a owns agent a (gather + gates + pointwise + pred).
__global__ void __launch_bounds__(256)
k_coop(const float* __restrict__ input, const float* __restrict__ h0,
       const float* __restrict__ c0, const void* __restrict__ mask,
       const float* __restrict__ pos_W, const float* __restrict__ pos_b,
       const float* __restrict__ soc_W, const float* __restrict__ soc_b,
       const float* __restrict__ out_W, const float* __restrict__ out_b,
       float* __restrict__ ws, const unsigned char* __restrict__ idx,
       const unsigned char* __restrict__ cnt, int CAP, float* __restrict__ d_out){
  cg::grid_group gg = cg::this_grid();
  const int mode = *(const int*)(ws + OFF_FLAG);
  const int a   = blockIdx.x;     // agent in phase B / column-block in phase A
  const int tid = threadIdx.x;

  float* S   = ws + OFF_S;
  float* hg  = ws + OFF_H;
  float* cgl = ws + OFF_C;

  __shared__ float Wl[128][4];    // soc_W slice for my 4 j-columns
  __shared__ float Xl[256];       // [pos | soc | h] row of my agent
  __shared__ float gl[512];       // gates row
  __shared__ float red[4][64];
  __shared__ float hn[128];

  // ---- prologue: cache W-slice, seed state ----
  const int j0 = a*4;
  for (int i = tid; i < 512; i += 256){
    int jj = i >> 7, hh = i & 127;
    int j = j0 + jj, g = j >> 6, e = j & 63;
    Wl[hh][jj] = soc_W[e*2048 + g*128 + hh];
  }
  if (tid < 128){
    hg[a*128+tid]  = h0[a*128+tid];
    cgl[a*128+tid] = c0[a*128+tid];
  }
  gg.sync();

  for (int t = 0; t < T_; t++){
    // ---- Phase A: S[k][j0..j0+3] = mask(t,k) * (h[k] . Wl) ----
    {
      const int k = tid;
      float mk = maskAt(mask, mode, t*A_ + k) ? 1.0f : 0.0f;
      float a0=0.f, a1=0.f, a2=0.f, a3=0.f;
      const float4* hp = (const float4*)(hg + k*128);
      #pragma unroll 4
      for (int c4 = 0; c4 < 32; c4++){
        float4 hv = hp[c4];
        int hh = c4*4;
        a0 += hv.x*Wl[hh][0] + hv.y*Wl[hh+1][0] + hv.z*Wl[hh+2][0] + hv.w*Wl[hh+3][0];
        a1 += hv.x*Wl[hh][1] + hv.y*Wl[hh+1][1] + hv.z*Wl[hh+2][1] + hv.w*Wl[hh+3][1];
        a2 += hv.x*Wl[hh][2] + hv.y*Wl[hh+1][2] + hv.z*Wl[hh+2][2] + hv.w*Wl[hh+3][2];
        a3 += hv.x*Wl[hh][3] + hv.y*Wl[hh+1][3] + hv.z*Wl[hh+2][3] + hv.w*Wl[hh+3][3];
      }
      float4 sv; sv.x = a0*mk; sv.y = a1*mk; sv.z = a2*mk; sv.w = a3*mk;
      *(float4*)(S + k*1024 + j0) = sv;
    }
    gg.sync();

    // ---- Phase B: agent a — gather soc, build X, gates, pointwise, pred ----
    {
      const int slot = tid >> 6, e = tid & 63;
      float acc = 0.0f;
      for (int g = slot*4; g < slot*4+4; g++){
        int row = (t*A_ + a)*GG_ + g;
        int c = cnt[row];
        const uint4* bp4 = (const uint4*)(idx + (size_t)row*CAP);
        for (int wq = 0; wq*16 < c; wq++){
          uint4 u = bp4[wq];
          int rem = c - wq*16; if (rem > 16) rem = 16;
          #pragma unroll
          for (int d=0; d<4; d++){
            unsigned uw = (d==0)?u.x:(d==1)?u.y:(d==2)?u.z:u.w;
            #pragma unroll
            for (int b=0; b<4; b++){
              int ii = d*4+b;
              if (ii < rem){
                int k = (uw >> (b*8)) & 255;
                acc += S[k*1024 + g*64 + e];
              }
            }
          }
        }
      }
      red[slot][e] = acc;
      if (tid >= 128) Xl[tid] = hg[a*128 + tid - 128];   // h part of X
      __syncthreads();
      if (tid < 64){
        float tot = red[0][e]+red[1][e]+red[2][e]+red[3][e];
        Xl[64+e] = fmaxf(tot + soc_b[e], 0.0f);
        float x0 = input[t*512 + a*2], x1 = input[t*512 + a*2 + 1];
        Xl[e] = fmaxf(x0*pos_W[e*2] + x1*pos_W[e*2+1] + pos_b[e], 0.0f);
      }
      __syncthreads();

      // gates: q = tid and q = tid+256, WcatT streamed from L2
      float g0 = 0.f, g1 = 0.f;
      const float* W0 = ws + OFF_WCATT + tid;
      #pragma unroll 8
      for (int col = 0; col < 256; col++){
        float x = Xl[col];
        g0 += x * W0[col*512];
        g1 += x * W0[col*512 + 256];
      }
      gl[tid]     = g0 + ws[OFF_BSUM + tid];
      gl[tid+256] = g1 + ws[OFF_BSUM + tid + 256];
      __syncthreads();

      const bool ma = maskAt(mask, mode, t*A_ + a);
      if (tid < 128){
        int hh = tid;
        float iv = sigf(gl[hh]);
        float fv = sigf(gl[128+hh]);
        float gv = tanhfast(gl[256+hh]);
        float ov = sigf(gl[384+hh]);
        float c_old = cgl[a*128+hh];
        float h_old = Xl[128+hh];
        float c_new = fv*c_old + iv*gv;
        float h_new = ov*tanhfast(c_new);
        float h_c = ma ? h_new : h_old;
        float c_c = ma ? c_new : c_old;
        hg[a*128+hh]  = h_c;
        cgl[a*128+hh] = c_c;
        hn[hh] = h_new;
        if (t == T_-1){
          d_out[32768 + a*128 + hh] = h_c;
          d_out[65536 + a*128 + hh] = c_c;
        }
      }
      __syncthreads();
      if (tid < 64){
        int r = tid & 1, hb = tid >> 1;   // 32 hb x 2 r
        float s = 0.f;
        #pragma unroll
        for (int q = 0; q < 4; q++){ int hh = hb + 32*q; s += hn[hh]*out_W[r*128+hh]; }
        s += __shfl_xor(s, 2);
        s += __shfl_xor(s, 4);
        s += __shfl_xor(s, 8);
        s += __shfl_xor(s, 16);
        s += __shfl_xor(s, 32);
        if (tid < 2){
          float p = s + out_b[r];
          d_out[t*512 + a*2 + r] = ma ? p : 0.0f;
        }
      }
    }
    gg.sync();
  }
}

extern "C" void kernel_launch(void* const* d_in, const int* in_sizes, int n_in,
                              void* d_out, int out_size, void* d_ws, size_t ws_size,
                              hipStream_t stream) {
  const float* input = (const float*)d_in[0];
  const float* grid  = (const float*)d_in[1];
  const float* h0    = (const float*)d_in[2];
  const float* c0    = (const float*)d_in[3];
  const void*  mask  = d_in[4];
  const float* pos_W = (const float*)d_in[5];
  const float* pos_b = (const float*)d_in[6];
  const float* soc_W = (const float*)d_in[7];
  const float* soc_b = (const float*)d_in[8];
  const float* W_ih  = (const float*)d_in[9];
  const float* W_hh  = (const float*)d_in[10];
  const float* b_ih  = (const float*)d_in[11];
  const float* b_hh  = (const float*)d_in[12];
  const float* out_W = (const float*)d_in[13];
  const float* out_b = (const float*)d_in[14];
  float* ws  = (float*)d_ws;
  float* out = (float*)d_out;

  const size_t NROWS = (size_t)T_*A_*GG_;   // 262144
  int CAP = 48;
  if (IDX_OFF_BYTES + NROWS*(size_t)CAP + NROWS > ws_size) CAP = 32;
  if (IDX_OFF_BYTES + NROWS*(size_t)CAP + NROWS > ws_size) CAP = 16;
  unsigned char* idx = (unsigned char*)d_ws + IDX_OFF_BYTES;
  unsigned char* cnt = idx + NROWS*(size_t)CAP;

  k_maskmode<<<1, 256, 0, stream>>>((const unsigned*)mask, (int*)(ws + OFF_FLAG));
  k_init<<<514, 256, 0, stream>>>(W_ih, W_hh, b_ih, b_hh, ws);
  k_encode<<<65536, 256, 0, stream>>>(grid, idx, cnt, CAP);

  int capv = CAP;
  void* args[] = {
    (void*)&input, (void*)&h0, (void*)&c0, (void*)&mask,
    (void*)&pos_W, (void*)&pos_b, (void*)&soc_W, (void*)&soc_b,
    (void*)&out_W, (void*)&out_b, (void*)&ws, (void*)&idx,
    (void*)&cnt, (void*)&capv, (void*)&out
  };
  hipLaunchCooperativeKernel((const void*)k_coop, dim3(256), dim3(256),
                             args, 0, stream);
}

// Round 6
// 3107.984 us; speedup vs baseline: 2.1169x; 2.1169x over previous
//
#include <hip/hip_runtime.h>
#include <stdint.h>

#define T_  64
#define A_  256
#define GG_ 16
#define H_  128

// ---- workspace layout (float offsets) ----
#define OFF_WCATT 0          // WcatT: [256 col][512 q]
#define OFF_WS2   131072     // Ws: [128 hh][1024 j]  (soc_W transposed)
#define OFF_BSUM  262144     // [512]
#define OFF_U0    262656     // U buf0: [256 k][1024 j]
#define OFF_U1    524800     // U buf1
#define OFF_FLAG  786944     // int: mask encoding mode
#define OFF_BAR   786945     // unsigned: barrier counter
#define IDX_OFF_BYTES 3147840ULL   // uint8 sparse indices (64B aligned)

__device__ __forceinline__ float sigf(float x){ return 1.0f/(1.0f+__expf(-x)); }
__device__ __forceinline__ float tanhfast(float x){ float e = __expf(2.0f*x); return 1.0f - 2.0f/(e+1.0f); }

__device__ __forceinline__ bool maskAt(const void* m, int mode, int i){
  if (mode == 0) return ((const int*)m)[i] != 0;
  if (mode == 2) return ((const float*)m)[i] != 0.0f;
  return ((const unsigned char*)m)[i] != 0;
}

// coherent (L2-bypassing) load — always sees other XCDs' published data
__device__ __forceinline__ float uload(const float* p){
  return __hip_atomic_load(p, __ATOMIC_RELAXED, __HIP_MEMORY_SCOPE_AGENT);
}

// release-only grid barrier: wbL2 to publish, NO invalidate (keeps weights L2-hot)
__device__ __forceinline__ void gbar(unsigned* bar, unsigned tgt){
  __syncthreads();
  if (threadIdx.x == 0){
    __builtin_amdgcn_fence(__ATOMIC_RELEASE, "agent");
    __hip_atomic_fetch_add(bar, 1u, __ATOMIC_RELAXED, __HIP_MEMORY_SCOPE_AGENT);
    while (__hip_atomic_load(bar, __ATOMIC_RELAXED, __HIP_MEMORY_SCOPE_AGENT) < tgt)
      __builtin_amdgcn_s_sleep(8);
  }
  __syncthreads();
}

// ---- detect mask encoding: 0=int32, 1=uint8/bool, 2=float32 ----
__global__ void k_maskmode(const unsigned* m, int* flag){
  __shared__ int r_int[256]; __shared__ int r_flt[256];
  int ok_int = 1, ok_flt = 1;
  for (int i = threadIdx.x; i < 4096; i += 256){
    unsigned v = m[i];
    if (v > 1u) ok_int = 0;
    if (v != 0u && v != 0x3F800000u) ok_flt = 0;
  }
  r_int[threadIdx.x]=ok_int; r_flt[threadIdx.x]=ok_flt; __syncthreads();
  for (int s=128;s>0;s>>=1){
    if (threadIdx.x<s){ r_int[threadIdx.x]&=r_int[threadIdx.x+s]; r_flt[threadIdx.x]&=r_flt[threadIdx.x+s]; }
    __syncthreads();
  }
  if (threadIdx.x==0) *flag = r_int[0] ? 0 : (r_flt[0] ? 2 : 1);
}

// ---- init: weight transposes, bias sum, barrier zero ----
__global__ void k_init(const float* __restrict__ soc_W, const float* __restrict__ W_ih,
                       const float* __restrict__ W_hh, const float* __restrict__ b_ih,
                       const float* __restrict__ b_hh, float* __restrict__ ws){
  const int n = 131072 + 131072 + 512 + 1;
  for (int id = blockIdx.x*blockDim.x + threadIdx.x; id < n; id += gridDim.x*blockDim.x){
    if (id < 131072){
      int col = id >> 9, q = id & 511;
      ws[OFF_WCATT + id] = (col < 128) ? W_ih[q*128+col] : W_hh[q*128+col-128];
    } else if (id < 262144){
      int i = id - 131072;
      int hh = i >> 10, j = i & 1023, g = j >> 6, eo = j & 63;
      ws[OFF_WS2 + i] = soc_W[eo*2048 + g*128 + hh];
    } else if (id < 262656){
      int q = id - 262144; ws[OFF_BSUM + q] = b_ih[q] + b_hh[q];
    } else {
      *(unsigned*)(ws + OFF_BAR) = 0u;
    }
  }
}

// ---- sparse-encode grid: per (t,a,g) row of 256, compact nonzero k (uint8) ----
__global__ void k_encode(const float* __restrict__ grid, unsigned char* __restrict__ idx,
                         unsigned char* __restrict__ cnt, int CAP){
  int wave = threadIdx.x >> 6, lane = threadIdx.x & 63;
  long long row = (long long)blockIdx.x*4 + wave;   // < 262144
  const float4 v = *(const float4*)(grid + row*256 + lane*4);
  unsigned long long lt = (lane == 0) ? 0ULL : ((1ULL << lane) - 1ULL);
  int base = 0;
  #pragma unroll
  for (int i=0;i<4;i++){
    float x = (i==0)?v.x:(i==1)?v.y:(i==2)?v.z:v.w;
    bool nz = (x != 0.0f);
    unsigned long long m = __ballot(nz);
    int pos = base + __popcll(m & lt);
    if (nz && pos < CAP) idx[(size_t)row*CAP + pos] = (unsigned char)(lane*4+i);
    base += __popcll(m);
  }
  if (lane==0) cnt[row] = (unsigned char)(base < CAP ? base : CAP);
}

// ---- persistent kernel: block a owns agent a for the whole recurrence ----
// 256 blocks x 512 threads; ONE release-only barrier per step.
__global__ void __launch_bounds__(512)
k_coop(const float* __restrict__ input, const float* __restrict__ h0,
       const float* __restrict__ c0, const void* __restrict__ mask,
       const float* __restrict__ pos_W, const float* __restrict__ pos_b,
       const float* __restrict__ soc_b, const float* __restrict__ out_W,
       const float* __restrict__ out_b, float* __restrict__ ws,
       const unsigned char* __restrict__ idx, const unsigned char* __restrict__ cnt,
       int CAP, float* __restrict__ d_out){
  const int mode = *(const int*)(ws + OFF_FLAG);
  const int a = blockIdx.x, tid = threadIdx.x;
  unsigned* bar = (unsigned*)(ws + OFF_BAR);

  __shared__ float hs[128], cs[128];   // block-local state (never re-read from global)
  __shared__ float Xl[256];            // [pos|soc|h]
  __shared__ float gl[512];            // gates
  __shared__ float red[8][64];
  __shared__ float hn[128];
  __shared__ unsigned long long mb[4]; // mask(t) bitmask

  // ---- prologue: seed state, publish U(-1) row = h0[a] @ Ws ----
  if (tid < 128){ hs[tid] = h0[a*128+tid]; cs[tid] = c0[a*128+tid]; }
  __syncthreads();
  {
    const float2* Wp = (const float2*)(ws + OFF_WS2) + tid;   // j0 = 2*tid
    float a0 = 0.f, a1 = 0.f;
    #pragma unroll 8
    for (int hh = 0; hh < 128; hh++){
      float hv = hs[hh];
      float2 w = Wp[(size_t)hh*512];
      a0 += hv*w.x; a1 += hv*w.y;
    }
    float2* Ud = (float2*)(ws + OFF_U0 + (size_t)a*1024) + tid;
    *Ud = make_float2(a0, a1);
  }
  gbar(bar, 256u*1);

  for (int t = 0; t < T_; t++){
    const float* Upar = ws + ((t & 1) ? OFF_U1 : OFF_U0);
    float* Ucur       = ws + ((t & 1) ? OFF_U0 : OFF_U1);

    // ---- mask bitmask for this step ----
    if (tid < 256){
      bool mv = maskAt(mask, mode, t*A_ + tid);
      unsigned long long b = __ballot(mv);
      if ((tid & 63) == 0) mb[tid >> 6] = b;
    }
    __syncthreads();

    // ---- gather soc from U (coherent loads, cross-XCD) ----
    {
      const int slot = tid >> 6, e = tid & 63;
      float acc = 0.0f;
      #pragma unroll
      for (int gi = 0; gi < 2; gi++){
        int g = slot*2 + gi;
        int row = (t*A_ + a)*GG_ + g;
        int c = cnt[row];
        const float* Ub = Upar + g*64 + e;
        const uint4* bp4 = (const uint4*)(idx + (size_t)row*CAP);
        for (int wq = 0; wq*16 < c; wq++){
          uint4 u = bp4[wq];
          int rem = c - wq*16; if (rem > 16) rem = 16;
          #pragma unroll
          for (int d=0; d<4; d++){
            unsigned uw = (d==0)?u.x:(d==1)?u.y:(d==2)?u.z:u.w;
            #pragma unroll
            for (int b2=0; b2<4; b2++){
              int ii = d*4+b2;
              if (ii < rem){
                int k = (uw >> (b2*8)) & 255;
                if ((mb[k>>6] >> (k&63)) & 1ULL) acc += uload(Ub + (size_t)k*1024);
              }
            }
          }
        }
      }
      red[slot][e] = acc;
    }
    __syncthreads();

    // ---- build X = [pos | soc | h(t-1)] ----
    if (tid < 64){
      int e = tid;
      float tot = red[0][e]+red[1][e]+red[2][e]+red[3][e]
                + red[4][e]+red[5][e]+red[6][e]+red[7][e];
      Xl[64+e] = fmaxf(tot + soc_b[e], 0.0f);
      float x0 = input[t*512 + a*2], x1 = input[t*512 + a*2 + 1];
      Xl[e] = fmaxf(x0*pos_W[e*2] + x1*pos_W[e*2+1] + pos_b[e], 0.0f);
    } else if (tid >= 128 && tid < 256){
      Xl[tid] = hs[tid-128];
    }
    __syncthreads();

    // ---- gates: q = tid over 512; WcatT stays L2-hot (no invalidates) ----
    {
      float ga = 0.f;
      const float* W0 = ws + OFF_WCATT + tid;
      #pragma unroll 16
      for (int col = 0; col < 256; col++) ga += Xl[col]*W0[(size_t)col*512];
      gl[tid] = ga + ws[OFF_BSUM + tid];
    }
    __syncthreads();

    // ---- pointwise LSTM ----
    const bool ma = (mb[a>>6] >> (a&63)) & 1ULL;
    if (tid < 128){
      int hh = tid;
      float iv = sigf(gl[hh]);
      float fv = sigf(gl[128+hh]);
      float gv = tanhfast(gl[256+hh]);
      float ov = sigf(gl[384+hh]);
      float c_old = cs[hh];
      float h_old = Xl[128+hh];
      float c_new = fv*c_old + iv*gv;
      float h_new = ov*tanhfast(c_new);
      float h_c = ma ? h_new : h_old;
      float c_c = ma ? c_new : c_old;
      hs[hh] = h_c; cs[hh] = c_c; hn[hh] = h_new;
      if (t == T_-1){
        d_out[32768 + a*128 + hh] = h_c;
        d_out[65536 + a*128 + hh] = c_c;
      }
    }
    __syncthreads();

    // ---- pred (threads<64) and publish U(t) row (all threads) ----
    if (tid < 64){
      int r = tid & 1, hb = tid >> 1;
      float s = 0.f;
      #pragma unroll
      for (int q = 0; q < 4; q++){ int hh = hb + 32*q; s += hn[hh]*out_W[r*128+hh]; }
      s += __shfl_xor(s, 2);
      s += __shfl_xor(s, 4);
      s += __shfl_xor(s, 8);
      s += __shfl_xor(s, 16);
      s += __shfl_xor(s, 32);
      if (tid < 2) d_out[t*512 + a*2 + r] = ma ? (s + out_b[r]) : 0.0f;
    }
    if (t < T_-1){
      const float2* Wp = (const float2*)(ws + OFF_WS2) + tid;
      float a0 = 0.f, a1 = 0.f;
      #pragma unroll 8
      for (int hh = 0; hh < 128; hh++){
        float hv = hs[hh];
        float2 w = Wp[(size_t)hh*512];
        a0 += hv*w.x; a1 += hv*w.y;
      }
      float2* Ud = (float2*)(Ucur + (size_t)a*1024) + tid;
      *Ud = make_float2(a0, a1);
      gbar(bar, 256u*(t+2));
    }
  }
}

extern "C" void kernel_launch(void* const* d_in, const int* in_sizes, int n_in,
                              void* d_out, int out_size, void* d_ws, size_t ws_size,
                              hipStream_t stream) {
  const float* input = (const float*)d_in[0];
  const float* grid  = (const float*)d_in[1];
  const float* h0    = (const float*)d_in[2];
  const float* c0    = (const float*)d_in[3];
  const void*  mask  = d_in[4];
  const float* pos_W = (const float*)d_in[5];
  const float* pos_b = (const float*)d_in[6];
  const float* soc_W = (const float*)d_in[7];
  const float* soc_b = (const float*)d_in[8];
  const float* W_ih  = (const float*)d_in[9];
  const float* W_hh  = (const float*)d_in[10];
  const float* b_ih  = (const float*)d_in[11];
  const float* b_hh  = (const float*)d_in[12];
  const float* out_W = (const float*)d_in[13];
  const float* out_b = (const float*)d_in[14];
  float* ws  = (float*)d_ws;
  float* out = (float*)d_out;

  const size_t NROWS = (size_t)T_*A_*GG_;   // 262144
  int CAP = 48;
  if (IDX_OFF_BYTES + NROWS*(size_t)CAP + NROWS > ws_size) CAP = 32;
  if (IDX_OFF_BYTES + NROWS*(size_t)CAP + NROWS > ws_size) CAP = 16;
  unsigned char* idx = (unsigned char*)d_ws + IDX_OFF_BYTES;
  unsigned char* cnt = idx + NROWS*(size_t)CAP;

  k_maskmode<<<1, 256, 0, stream>>>((const unsigned*)mask, (int*)(ws + OFF_FLAG));
  k_init<<<1026, 256, 0, stream>>>(soc_W, W_ih, W_hh, b_ih, b_hh, ws);
  k_encode<<<65536, 256, 0, stream>>>(grid, idx, cnt, CAP);

  int capv = CAP;
  void* args[] = {
    (void*)&input, (void*)&h0, (void*)&c0, (void*)&mask,
    (void*)&pos_W, (void*)&pos_b, (void*)&soc_b,
    (void*)&out_W, (void*)&out_b, (void*)&ws, (void*)&idx,
    (void*)&cnt, (void*)&capv, (void*)&out
  };
  hipLaunchCooperativeKernel((const void*)k_coop, dim3(256), dim3(512),
                             args, 0, stream);
}

// Round 8
// 2302.205 us; speedup vs baseline: 2.8578x; 1.3500x over previous
//
#include <hip/hip_runtime.h>
#include <stdint.h>

#define T_  64
#define A_  256
#define GG_ 16
#define H_  128

// ---- workspace layout (float offsets) ----
#define OFF_WCATT 0          // WcatT: [256 col][512 q]
#define OFF_WS2   131072     // Ws: [128 hh][1024 j]  (soc_W transposed)
#define OFF_BSUM  262144     // [512]
#define OFF_U0    262656     // U buf0: [256 k][1024 j]
#define OFF_U1    524800     // U buf1
#define OFF_FLAG  786944     // int: mask encoding mode
#define OFF_BAR   786945     // unsigned: barrier counter
#define IDX_OFF_BYTES 3147840ULL   // uint8 sparse indices (64B aligned)

__device__ __forceinline__ float sigf(float x){ return 1.0f/(1.0f+__expf(-x)); }
__device__ __forceinline__ float tanhfast(float x){ float e = __expf(2.0f*x); return 1.0f - 2.0f/(e+1.0f); }

__device__ __forceinline__ bool maskAt(const void* m, int mode, int i){
  if (mode == 0) return ((const int*)m)[i] != 0;
  if (mode == 2) return ((const float*)m)[i] != 0.0f;
  return ((const unsigned char*)m)[i] != 0;
}

// coherent (L2-bypassing) load — always sees other XCDs' published data
__device__ __forceinline__ float uload(const float* p){
  return __hip_atomic_load(p, __ATOMIC_RELAXED, __HIP_MEMORY_SCOPE_AGENT);
}

// write-through coherent store of 8 bytes
__device__ __forceinline__ void ustore2(float* p, float x, float y){
  union { float2 f; unsigned long long u; } cv;
  cv.f = make_float2(x, y);
  __hip_atomic_store((unsigned long long*)p, cv.u, __ATOMIC_RELAXED, __HIP_MEMORY_SCOPE_AGENT);
}

// grid barrier: RELEASE arrival (compiler emits minimal fence; dirty L2 set is
// tiny since U goes write-through), relaxed poll with short sleep.
__device__ __forceinline__ void gbar(unsigned* bar, unsigned tgt){
  __syncthreads();
  if (threadIdx.x == 0){
    __hip_atomic_fetch_add(bar, 1u, __ATOMIC_RELEASE, __HIP_MEMORY_SCOPE_AGENT);
    while (__hip_atomic_load(bar, __ATOMIC_RELAXED, __HIP_MEMORY_SCOPE_AGENT) < tgt)
      __builtin_amdgcn_s_sleep(1);
  }
  __syncthreads();
}

// ---- detect mask encoding: 0=int32, 1=uint8/bool, 2=float32 ----
__global__ void k_maskmode(const unsigned* m, int* flag){
  __shared__ int r_int[256]; __shared__ int r_flt[256];
  int ok_int = 1, ok_flt = 1;
  for (int i = threadIdx.x; i < 4096; i += 256){
    unsigned v = m[i];
    if (v > 1u) ok_int = 0;
    if (v != 0u && v != 0x3F800000u) ok_flt = 0;
  }
  r_int[threadIdx.x]=ok_int; r_flt[threadIdx.x]=ok_flt; __syncthreads();
  for (int s=128;s>0;s>>=1){
    if (threadIdx.x<s){ r_int[threadIdx.x]&=r_int[threadIdx.x+s]; r_flt[threadIdx.x]&=r_flt[threadIdx.x+s]; }
    __syncthreads();
  }
  if (threadIdx.x==0) *flag = r_int[0] ? 0 : (r_flt[0] ? 2 : 1);
}

// ---- init: weight transposes, bias sum, barrier zero ----
__global__ void k_init(const float* __restrict__ soc_W, const float* __restrict__ W_ih,
                       const float* __restrict__ W_hh, const float* __restrict__ b_ih,
                       const float* __restrict__ b_hh, float* __restrict__ ws){
  const int n = 131072 + 131072 + 512 + 1;
  for (int id = blockIdx.x*blockDim.x + threadIdx.x; id < n; id += gridDim.x*blockDim.x){
    if (id < 131072){
      int col = id >> 9, q = id & 511;
      ws[OFF_WCATT + id] = (col < 128) ? W_ih[q*128+col] : W_hh[q*128+col-128];
    } else if (id < 262144){
      int i = id - 131072;
      int hh = i >> 10, j = i & 1023, g = j >> 6, eo = j & 63;
      ws[OFF_WS2 + i] = soc_W[eo*2048 + g*128 + hh];
    } else if (id < 262656){
      int q = id - 262144; ws[OFF_BSUM + q] = b_ih[q] + b_hh[q];
    } else {
      *(unsigned*)(ws + OFF_BAR) = 0u;
    }
  }
}

// ---- sparse-encode grid: per (t,a,g) row of 256, compact nonzero k (uint8) ----
__global__ void k_encode(const float* __restrict__ grid, unsigned char* __restrict__ idx,
                         unsigned char* __restrict__ cnt, int CAP){
  int wave = threadIdx.x >> 6, lane = threadIdx.x & 63;
  long long row = (long long)blockIdx.x*4 + wave;   // < 262144
  const float4 v = *(const float4*)(grid + row*256 + lane*4);
  unsigned long long lt = (lane == 0) ? 0ULL : ((1ULL << lane) - 1ULL);
  int base = 0;
  #pragma unroll
  for (int i=0;i<4;i++){
    float x = (i==0)?v.x:(i==1)?v.y:(i==2)?v.z:v.w;
    bool nz = (x != 0.0f);
    unsigned long long m = __ballot(nz);
    int pos = base + __popcll(m & lt);
    if (nz && pos < CAP) idx[(size_t)row*CAP + pos] = (unsigned char)(lane*4+i);
    base += __popcll(m);
  }
  if (lane==0) cnt[row] = (unsigned char)(base < CAP ? base : CAP);
}

// ---- persistent kernel: block a owns agent a; one barrier per step ----
__global__ void __launch_bounds__(512)
k_coop(const float* __restrict__ input, const float* __restrict__ h0,
       const float* __restrict__ c0, const void* __restrict__ mask,
       const float* __restrict__ pos_W, const float* __restrict__ pos_b,
       const float* __restrict__ soc_b, const float* __restrict__ out_W,
       const float* __restrict__ out_b, float* __restrict__ ws,
       const unsigned char* __restrict__ idx, const unsigned char* __restrict__ cnt,
       int CAP, float* __restrict__ d_out){
  const int mode = *(const int*)(ws + OFF_FLAG);
  const int a = blockIdx.x, tid = threadIdx.x;
  unsigned* bar = (unsigned*)(ws + OFF_BAR);

  __shared__ float hs[128], cs[128];   // block-local state
  __shared__ float Xl[256];            // [pos|soc|h]
  __shared__ float gl[512];            // gates
  __shared__ float red[8][64];
  __shared__ float hn[128];

  // ---- prologue: seed state, publish U(-1) row = mask(0,a) * h0[a] @ Ws ----
  if (tid < 128){ hs[tid] = h0[a*128+tid]; cs[tid] = c0[a*128+tid]; }
  __syncthreads();
  {
    float mpub = maskAt(mask, mode, a) ? 1.0f : 0.0f;
    const float2* Wp = (const float2*)(ws + OFF_WS2) + tid;   // j0 = 2*tid
    float a0 = 0.f, a1 = 0.f;
    #pragma unroll 8
    for (int hh = 0; hh < 128; hh++){
      float hv = hs[hh];
      float2 w = Wp[(size_t)hh*512];
      a0 += hv*w.x; a1 += hv*w.y;
    }
    ustore2(ws + OFF_U0 + (size_t)a*1024 + 2*tid, a0*mpub, a1*mpub);
  }
  gbar(bar, 256u*1);

  for (int t = 0; t < T_; t++){
    const float* Upar = ws + ((t & 1) ? OFF_U1 : OFF_U0);
    float* Ucur       = ws + ((t & 1) ? OFF_U0 : OFF_U1);

    // ---- gather soc from U: branch-free batched coherent loads ----
    {
      const int slot = tid >> 6, e = tid & 63;
      float acc = 0.0f;
      #pragma unroll
      for (int gi = 0; gi < 2; gi++){
        int g = slot*2 + gi;
        int row = (t*A_ + a)*GG_ + g;
        int c = cnt[row];
        const float* Ub = Upar + g*64 + e;
        const uint4* bp4 = (const uint4*)(idx + (size_t)row*CAP);
        int nb = (c + 15) >> 4;
        for (int wq = 0; wq < nb; wq++){
          uint4 u = bp4[wq];
          unsigned kk[16]; float v[16];
          #pragma unroll
          for (int d=0; d<4; d++){
            unsigned uw = (d==0)?u.x:(d==1)?u.y:(d==2)?u.z:u.w;
            #pragma unroll
            for (int b2=0; b2<4; b2++) kk[d*4+b2] = (uw >> (b2*8)) & 255u;
          }
          #pragma unroll
          for (int ii=0; ii<16; ii++) v[ii] = uload(Ub + (size_t)kk[ii]*1024);
          int base = wq*16;
          #pragma unroll
          for (int ii=0; ii<16; ii++) acc += (base + ii < c) ? v[ii] : 0.0f;
        }
      }
      red[slot][e] = acc;
      // prefetch next step's idx/cnt rows into L2 (keep-alive, no DCE)
      if (t < T_-1 && e == 0){
        int row2 = ((t+1)*A_ + a)*GG_ + slot*2;
        unsigned cpr = cnt[row2];
        uint4 upr = *(const uint4*)(idx + (size_t)row2*CAP);
        asm volatile("" :: "v"(cpr), "v"(upr.x));
      }
    }
    __syncthreads();

    // ---- build X = [pos | soc | h(t-1)] ----
    if (tid < 64){
      int e = tid;
      float tot = red[0][e]+red[1][e]+red[2][e]+red[3][e]
                + red[4][e]+red[5][e]+red[6][e]+red[7][e];
      Xl[64+e] = fmaxf(tot + soc_b[e], 0.0f);
      float x0 = input[t*512 + a*2], x1 = input[t*512 + a*2 + 1];
      Xl[e] = fmaxf(x0*pos_W[e*2] + x1*pos_W[e*2+1] + pos_b[e], 0.0f);
    } else if (tid >= 128 && tid < 256){
      Xl[tid] = hs[tid-128];
    }
    __syncthreads();

    // ---- gates: q = tid over 512; WcatT stays L2-hot ----
    {
      float ga = 0.f;
      const float* W0 = ws + OFF_WCATT + tid;
      #pragma unroll 16
      for (int col = 0; col < 256; col++) ga += Xl[col]*W0[(size_t)col*512];
      gl[tid] = ga + ws[OFF_BSUM + tid];
    }
    __syncthreads();

    // ---- pointwise LSTM ----
    const bool ma = maskAt(mask, mode, t*A_ + a);
    if (tid < 128){
      int hh = tid;
      float iv = sigf(gl[hh]);
      float fv = sigf(gl[128+hh]);
      float gv = tanhfast(gl[256+hh]);
      float ov = sigf(gl[384+hh]);
      float c_old = cs[hh];
      float h_old = Xl[128+hh];
      float c_new = fv*c_old + iv*gv;
      float h_new = ov*tanhfast(c_new);
      float h_c = ma ? h_new : h_old;
      float c_c = ma ? c_new : c_old;
      hs[hh] = h_c; cs[hh] = c_c; hn[hh] = h_new;
      if (t == T_-1){
        d_out[32768 + a*128 + hh] = h_c;
        d_out[65536 + a*128 + hh] = c_c;
      }
    }
    __syncthreads();

    // ---- pred (threads<64) and publish U(t) row with mask(t+1) folded in ----
    if (tid < 64){
      int r = tid & 1, hb = tid >> 1;
      float s = 0.f;
      #pragma unroll
      for (int q = 0; q < 4; q++){ int hh = hb + 32*q; s += hn[hh]*out_W[r*128+hh]; }
      s += __shfl_xor(s, 2);
      s += __shfl_xor(s, 4);
      s += __shfl_xor(s, 8);
      s += __shfl_xor(s, 16);
      s += __shfl_xor(s, 32);
      if (tid < 2) d_out[t*512 + a*2 + r] = ma ? (s + out_b[r]) : 0.0f;
    }
    if (t < T_-1){
      float mpub = maskAt(mask, mode, (t+1)*A_ + a) ? 1.0f : 0.0f;
      const float2* Wp = (const float2*)(ws + OFF_WS2) + tid;
      float a0 = 0.f, a1 = 0.f;
      #pragma unroll 8
      for (int hh = 0; hh < 128; hh++){
        float hv = hs[hh];
        float2 w = Wp[(size_t)hh*512];
        a0 += hv*w.x; a1 += hv*w.y;
      }
      ustore2(Ucur + (size_t)a*1024 + 2*tid, a0*mpub, a1*mpub);
      gbar(bar, 256u*(t+2));
    }
  }
}

extern "C" void kernel_launch(void* const* d_in, const int* in_sizes, int n_in,
                              void* d_out, int out_size, void* d_ws, size_t ws_size,
                              hipStream_t stream) {
  const float* input = (const float*)d_in[0];
  const float* grid  = (const float*)d_in[1];
  const float* h0    = (const float*)d_in[2];
  const float* c0    = (const float*)d_in[3];
  const void*  mask  = d_in[4];
  const float* pos_W = (const float*)d_in[5];
  const float* pos_b = (const float*)d_in[6];
  const float* soc_W = (const float*)d_in[7];
  const float* soc_b = (const float*)d_in[8];
  const float* W_ih  = (const float*)d_in[9];
  const float* W_hh  = (const float*)d_in[10];
  const float* b_ih  = (const float*)d_in[11];
  const float* b_hh  = (const float*)d_in[12];
  const float* out_W = (const float*)d_in[13];
  const float* out_b = (const float*)d_in[14];
  float* ws  = (float*)d_ws;
  float* out = (float*)d_out;

  const size_t NROWS = (size_t)T_*A_*GG_;   // 262144
  int CAP = 48;
  if (IDX_OFF_BYTES + NROWS*(size_t)CAP + NROWS > ws_size) CAP = 32;
  if (IDX_OFF_BYTES + NROWS*(size_t)CAP + NROWS > ws_size) CAP = 16;
  unsigned char* idx = (unsigned char*)d_ws + IDX_OFF_BYTES;
  unsigned char* cnt = idx + NROWS*(size_t)CAP;

  k_maskmode<<<1, 256, 0, stream>>>((const unsigned*)mask, (int*)(ws + OFF_FLAG));
  k_init<<<1026, 256, 0, stream>>>(soc_W, W_ih, W_hh, b_ih, b_hh, ws);
  k_encode<<<65536, 256, 0, stream>>>(grid, idx, cnt, CAP);

  int capv = CAP;
  void* args[] = {
    (void*)&input, (void*)&h0, (void*)&c0, (void*)&mask,
    (void*)&pos_W, (void*)&pos_b, (void*)&soc_b,
    (void*)&out_W, (void*)&out_b, (void*)&ws, (void*)&idx,
    (void*)&cnt, (void*)&capv, (void*)&out
  };
  hipLaunchCooperativeKernel((const void*)k_coop, dim3(256), dim3(512),
                             args, 0, stream);
}